// Round 7
// baseline (225.377 us; speedup 1.0000x reference)
//
#include <hip/hip_runtime.h>
#include <hip/hip_bf16.h>

#define CATS 17
#define SCALES 5
#define DIM 256
#define NSEG (CATS * SCALES)   // 85
#define TEMP 0.07f
#define GPARTS 12              // gather blocks per segment: grid = 85*12 = 1020
#define CHUNK_ROWS 4096        // rows per build block (256 thr x 16)

// ws layout (bytes): numAcc@0 | doneCtr@4 | gCnt@8 | pad | sums@512 | idx@87552
// ---------------------------------------------------------------------------
// Kernel 0: build compact per-segment row-id lists. Block 0 also zeroes sums.
// ---------------------------------------------------------------------------
__global__ __launch_bounds__(256)
void build_kernel(const int* __restrict__ tgt, const int* __restrict__ lvl,
                  int* __restrict__ idx, int* __restrict__ gCnt,
                  float* __restrict__ sums,
                  int n, int idxStride) {
    __shared__ int hist[NSEG];
    __shared__ int baseb[NSEG];

    const int t  = threadIdx.x;
    const int r0 = blockIdx.x * CHUNK_ROWS;
    const int rbase = r0 + t * 16;

    if (blockIdx.x == 0) {   // zero the sums accumulator (gather runs next)
        float4 z = make_float4(0.f, 0.f, 0.f, 0.f);
        for (int i = t; i < NSEG * DIM / 4; i += 256)
            reinterpret_cast<float4*>(sums)[i] = z;
    }

    for (int i = t; i < NSEG; i += 256) hist[i] = 0;
    __syncthreads();

    int segv[16];
    if (rbase + 16 <= n) {
        #pragma unroll
        for (int q = 0; q < 4; ++q) {
            const int4 tv = *reinterpret_cast<const int4*>(tgt + rbase + q * 4);
            const int4 lv = *reinterpret_cast<const int4*>(lvl + rbase + q * 4);
            segv[q * 4 + 0] = tv.x * SCALES + lv.x;
            segv[q * 4 + 1] = tv.y * SCALES + lv.y;
            segv[q * 4 + 2] = tv.z * SCALES + lv.z;
            segv[q * 4 + 3] = tv.w * SCALES + lv.w;
        }
    } else {
        #pragma unroll
        for (int k = 0; k < 16; ++k)
            segv[k] = (rbase + k < n)
                    ? tgt[rbase + k] * SCALES + lvl[rbase + k] : -1;
    }

    #pragma unroll
    for (int k = 0; k < 16; ++k)
        if (segv[k] >= 0) atomicAdd(&hist[segv[k]], 1);
    __syncthreads();

    for (int i = t; i < NSEG; i += 256)
        baseb[i] = atomicAdd(&gCnt[i], hist[i]);
    __syncthreads();
    for (int i = t; i < NSEG; i += 256) hist[i] = 0;   // reuse as rank ctrs
    __syncthreads();

    #pragma unroll
    for (int k = 0; k < 16; ++k) {
        const int s = segv[k];
        if (s >= 0) {
            const int rk = atomicAdd(&hist[s], 1);
            idx[(size_t)s * idxStride + baseb[s] + rk] = rbase + k;
        }
    }
}

// ---------------------------------------------------------------------------
// Kernel 1: pure streaming gather, scalar row-ids.
// readfirstlane(e) makes the id-list address uniform -> s_load of 8 ids into
// SGPRs; each feature-row address is SGPR base + shared lane*16 voffset.
// Hot loop contains nothing but scalar id loads, 8-deep dwordx4 row loads,
// and v_add accumulates. Register-only accumulation; tiny atomic flush.
// ---------------------------------------------------------------------------
__global__ __launch_bounds__(256)
void gather_kernel(const float* __restrict__ feats,
                   const int* __restrict__ idx,
                   const int* __restrict__ gCnt,
                   float* __restrict__ sums,     // [NSEG][DIM]
                   int idxStride) {
    const int bid  = blockIdx.x;
    const int g    = bid / GPARTS;
    const int p    = bid - g * GPARTS;
    const int lane = threadIdx.x & 63;
    const int wave = threadIdx.x >> 6;

    const int cnt   = gCnt[g];
    const int chunk = (cnt + GPARTS - 1) / GPARTS;
    const int e0    = p * chunk;
    const int e1    = min(e0 + chunk, cnt);
    const int* lst  = idx + (size_t)g * idxStride;

    float4 a0 = make_float4(0.f, 0.f, 0.f, 0.f), a1 = a0, a2 = a0, a3 = a0;
    float4 a4 = a0, a5 = a0, a6 = a0, a7 = a0;

    for (int e = e0 + wave * 64; e < e1; e += 256) {
        const int eu = __builtin_amdgcn_readfirstlane(e);
        const int m  = min(64, e1 - eu);

        if (m == 64) {
            #pragma unroll
            for (int j0 = 0; j0 < 64; j0 += 8) {
                int id[8];
                #pragma unroll
                for (int u = 0; u < 8; ++u) id[u] = lst[eu + j0 + u];
                float4 v[8];
                #pragma unroll
                for (int u = 0; u < 8; ++u)
                    v[u] = *reinterpret_cast<const float4*>(
                        feats + (size_t)id[u] * DIM + lane * 4);
                a0.x += v[0].x; a0.y += v[0].y; a0.z += v[0].z; a0.w += v[0].w;
                a1.x += v[1].x; a1.y += v[1].y; a1.z += v[1].z; a1.w += v[1].w;
                a2.x += v[2].x; a2.y += v[2].y; a2.z += v[2].z; a2.w += v[2].w;
                a3.x += v[3].x; a3.y += v[3].y; a3.z += v[3].z; a3.w += v[3].w;
                a4.x += v[4].x; a4.y += v[4].y; a4.z += v[4].z; a4.w += v[4].w;
                a5.x += v[5].x; a5.y += v[5].y; a5.z += v[5].z; a5.w += v[5].w;
                a6.x += v[6].x; a6.y += v[6].y; a6.z += v[6].z; a6.w += v[6].w;
                a7.x += v[7].x; a7.y += v[7].y; a7.z += v[7].z; a7.w += v[7].w;
            }
        } else {
            for (int j0 = 0; j0 < m; j0 += 8) {
                int id[8]; float sc[8];
                #pragma unroll
                for (int u = 0; u < 8; ++u) {
                    const int jj = j0 + u;
                    const int jc = (jj < m) ? jj : (m - 1);
                    sc[u] = (jj < m) ? 1.f : 0.f;
                    id[u] = lst[eu + jc];
                }
                float4 v[8];
                #pragma unroll
                for (int u = 0; u < 8; ++u)
                    v[u] = *reinterpret_cast<const float4*>(
                        feats + (size_t)id[u] * DIM + lane * 4);
                a0.x = fmaf(v[0].x, sc[0], a0.x); a0.y = fmaf(v[0].y, sc[0], a0.y);
                a0.z = fmaf(v[0].z, sc[0], a0.z); a0.w = fmaf(v[0].w, sc[0], a0.w);
                a1.x = fmaf(v[1].x, sc[1], a1.x); a1.y = fmaf(v[1].y, sc[1], a1.y);
                a1.z = fmaf(v[1].z, sc[1], a1.z); a1.w = fmaf(v[1].w, sc[1], a1.w);
                a2.x = fmaf(v[2].x, sc[2], a2.x); a2.y = fmaf(v[2].y, sc[2], a2.y);
                a2.z = fmaf(v[2].z, sc[2], a2.z); a2.w = fmaf(v[2].w, sc[2], a2.w);
                a3.x = fmaf(v[3].x, sc[3], a3.x); a3.y = fmaf(v[3].y, sc[3], a3.y);
                a3.z = fmaf(v[3].z, sc[3], a3.z); a3.w = fmaf(v[3].w, sc[3], a3.w);
                a4.x = fmaf(v[4].x, sc[4], a4.x); a4.y = fmaf(v[4].y, sc[4], a4.y);
                a4.z = fmaf(v[4].z, sc[4], a4.z); a4.w = fmaf(v[4].w, sc[4], a4.w);
                a5.x = fmaf(v[5].x, sc[5], a5.x); a5.y = fmaf(v[5].y, sc[5], a5.y);
                a5.z = fmaf(v[5].z, sc[5], a5.z); a5.w = fmaf(v[5].w, sc[5], a5.w);
                a6.x = fmaf(v[6].x, sc[6], a6.x); a6.y = fmaf(v[6].y, sc[6], a6.y);
                a6.z = fmaf(v[6].z, sc[6], a6.z); a6.w = fmaf(v[6].w, sc[6], a6.w);
                a7.x = fmaf(v[7].x, sc[7], a7.x); a7.y = fmaf(v[7].y, sc[7], a7.y);
                a7.z = fmaf(v[7].z, sc[7], a7.z); a7.w = fmaf(v[7].w, sc[7], a7.w);
            }
        }
    }

    a0.x += a1.x + a2.x + a3.x + a4.x + a5.x + a6.x + a7.x;
    a0.y += a1.y + a2.y + a3.y + a4.y + a5.y + a6.y + a7.y;
    a0.z += a1.z + a2.z + a3.z + a4.z + a5.z + a6.z + a7.z;
    a0.w += a1.w + a2.w + a3.w + a4.w + a5.w + a6.w + a7.w;

    float* dst = sums + (size_t)g * DIM + lane * 4;
    unsafeAtomicAdd(dst + 0, a0.x);
    unsafeAtomicAdd(dst + 1, a0.y);
    unsafeAtomicAdd(dst + 2, a0.z);
    unsafeAtomicAdd(dst + 3, a0.w);
}

// ---------------------------------------------------------------------------
// Kernel 2: InfoNCE head + fused last-block finalize.
// One block (64 lanes) per output row cs = c*5+s; the 85th block to finish
// computes the final loss (threadfence + done-counter handshake).
// ---------------------------------------------------------------------------
__global__ void infonce_kernel(const float* __restrict__ protos,  // [NSEG][DIM]
                               const float* __restrict__ sums,    // [NSEG][DIM]
                               const int* __restrict__ gCnt,      // [NSEG]
                               float* __restrict__ numAcc,
                               unsigned* __restrict__ doneCtr,
                               float* __restrict__ out) {
    const int cs   = blockIdx.x;        // c*SCALES + s
    const int s    = cs % SCALES;
    const int lane = threadIdx.x;       // 0..63, 4 dims each

    const float4 p = *reinterpret_cast<const float4*>(
        protos + (size_t)cs * DIM + lane * 4);
    float ssq1 = p.x * p.x + p.y * p.y + p.z * p.z + p.w * p.w;
    #pragma unroll
    for (int off = 32; off > 0; off >>= 1) ssq1 += __shfl_down(ssq1, off);
    ssq1 = __shfl(ssq1, 0);

    float logits[CATS];
    for (int k = 0; k < CATS; ++k) {
        const int r2 = k * SCALES + s;
        const int cntv = gCnt[r2];
        float4 dv;
        if (cntv > 0) {
            const float4 sm = *reinterpret_cast<const float4*>(
                sums + (size_t)r2 * DIM + lane * 4);
            const float inv = 1.f / (float)cntv;
            dv = make_float4(sm.x * inv, sm.y * inv, sm.z * inv, sm.w * inv);
        } else {
            dv = make_float4(0.01f, 0.01f, 0.01f, 0.01f);
        }
        float ssq2 = dv.x * dv.x + dv.y * dv.y + dv.z * dv.z + dv.w * dv.w;
        float dot  = p.x * dv.x + p.y * dv.y + p.z * dv.z + p.w * dv.w;
        #pragma unroll
        for (int off = 32; off > 0; off >>= 1) {
            ssq2 += __shfl_down(ssq2, off);
            dot  += __shfl_down(dot, off);
        }
        const float lg = dot / (sqrtf(ssq2) * sqrtf(ssq1) * TEMP);
        logits[k] = __shfl(lg, 0);
    }

    if (lane == 0) {
        float mx = logits[0];
        #pragma unroll
        for (int k = 1; k < CATS; ++k) mx = fmaxf(mx, logits[k]);
        float sum = 0.f;
        #pragma unroll
        for (int k = 0; k < CATS; ++k) sum += expf(logits[k] - mx);
        const float lse     = mx + logf(sum);
        const int   label   = cs % CATS;
        const float per_row = lse - logits[label];
        unsafeAtomicAdd(numAcc, (gCnt[cs] > 0) ? per_row : 0.f);
        __threadfence();
        const unsigned done = atomicAdd(doneCtr, 1u);
        if (done == NSEG - 1) {           // last block finalizes
            __threadfence();
            float msum = 0.f;
            for (int i = 0; i < NSEG; ++i) msum += (gCnt[i] > 0) ? 1.f : 0.f;
            const float total = unsafeAtomicAdd(numAcc, 0.f);  // atomic read
            out[0] = total / fmaxf(msum, 1.f);
        }
    }
}

extern "C" void kernel_launch(void* const* d_in, const int* in_sizes, int n_in,
                              void* d_out, int out_size, void* d_ws, size_t ws_size,
                              hipStream_t stream) {
    const float* feats  = (const float*)d_in[0];   // [N][256] f32
    const int*   tgt    = (const int*)d_in[1];     // [N] int32
    const int*   lvl    = (const int*)d_in[2];     // [N] int32
    const float* protos = (const float*)d_in[3];   // [17][5][256] f32
    float* out = (float*)d_out;

    const int n = in_sizes[1];                     // N rows

    // ws: numAcc@0 | doneCtr@4 | gCnt@8 | sums@512 | idx@87552 (128-aligned)
    float*    numAcc  = (float*)d_ws;
    unsigned* doneCtr = (unsigned*)((char*)d_ws + 4);
    int*      gCnt    = (int*)((char*)d_ws + 8);
    float*    sums    = (float*)((char*)d_ws + 512);
    int*      idx     = (int*)((char*)d_ws + 512 + (size_t)NSEG * DIM * 4);

    // zero numAcc + doneCtr + gCnt only (sums zeroed by build block 0)
    hipMemsetAsync(d_ws, 0, 8 + (size_t)NSEG * 4, stream);

    const int nBuild = (n + CHUNK_ROWS - 1) / CHUNK_ROWS;
    build_kernel<<<nBuild, 256, 0, stream>>>(tgt, lvl, idx, gCnt, sums, n, n);
    gather_kernel<<<NSEG * GPARTS, 256, 0, stream>>>(feats, idx, gCnt, sums, n);
    infonce_kernel<<<NSEG, 64, 0, stream>>>(protos, sums, gCnt, numAcc,
                                            doneCtr, out);
}